// Round 16
// baseline (608.196 us; speedup 1.0000x reference)
//
#include <hip/hip_runtime.h>
#include <math.h>

constexpr int Bq  = 8;
constexpr int NGq = 16384;
constexpr int Nq  = Bq * NGq;       // 131072 nodes
constexpr int Eq  = Nq * 16;        // 2097152 edges
constexpr int Eg  = Eq / 8;         // 262144 edges per graph
constexpr int BCAP = 8192;          // fixed bucket capacity (mean 4096, sd 64)

// partial-buffer float offsets (compact-fused readout partials)
constexpr int P1 = 0;               // 4096 blocks x 128
constexpr int P2 = 524288;          // 2048 x 128
constexpr int P3 = 786432;          // 1024 x 128
constexpr int P4 = 917504;          //  512 x 128
constexpr int PTOT = 983040;

__device__ __forceinline__ unsigned mono_key(float s) {
    unsigned u = __float_as_uint(s);
    return u ^ ((u >> 31) ? 0xFFFFFFFFu : 0x80000000u);
}

// ---------------------------------------------------------------------------
// One-time prep: weight transposes + wp norms + bcur zero + ghist zero.
// ---------------------------------------------------------------------------
__global__ void k_prep(const float* __restrict__ Wl2, const float* __restrict__ Wr2,
                       const float* __restrict__ W4, const float* __restrict__ W5,
                       const float* __restrict__ Wa, const float* __restrict__ Wb,
                       const float* __restrict__ Wc,
                       const float* __restrict__ w1, const float* __restrict__ w2,
                       const float* __restrict__ w4p, const float* __restrict__ w5p,
                       float* __restrict__ wT, float* __restrict__ wMT,
                       float* __restrict__ winv, int* __restrict__ bcur,
                       int* __restrict__ ghist) {
    int t = threadIdx.x, b = blockIdx.x;
    if (b < 4) {
        const float* in = (b == 0) ? Wl2 : (b == 1) ? Wr2 : (b == 2) ? W4 : W5;
        float* out = wT + (size_t)b * 4096;
        for (int i = t; i < 4096; i += 256) {
            int r = i >> 6, c = i & 63;
            out[c * 64 + r] = in[r * 64 + c];
        }
    } else if (b == 4) {
        float* WaT = wMT;
        for (int i = t; i < 16384; i += 256) {
            int r = i >> 7, c = i & 127;
            WaT[c * 128 + r] = Wa[r * 128 + c];
        }
    } else if (b == 5) {
        float* WbT = wMT + 16384;
        for (int i = t; i < 8192; i += 256) {
            int r = i >> 7, c = i & 127;
            WbT[c * 64 + r] = Wb[r * 128 + c];
        }
    } else if (b == 6) {
        float* WcT = wMT + 16384 + 8192;
        for (int i = t; i < 16384; i += 256) {
            int r = i >> 6, c = i & 63;
            WcT[c * 256 + r] = Wc[r * 64 + c];
        }
    } else {
        int vsel = t >> 6, lane = t & 63;
        const float* wp = (vsel == 0) ? w1 : (vsel == 1) ? w2 : (vsel == 2) ? w4p : w5p;
        float v = wp[lane];
        float ww = v * v;
        for (int o = 32; o; o >>= 1) ww += __shfl_xor(ww, o);
        if (lane == 0) winv[vsel] = 1.0f / sqrtf(ww);
        for (int i = t; i < 512; i += 256) bcur[i] = 0;
        for (int i = t; i < 8192; i += 256) ghist[i] = 0;   // 4 rounds x 8 graphs x 256
    }
}

// ---------------------------------------------------------------------------
// CSR build: fixed-capacity buckets (bucket = dst>>8, region b*BCAP).
// ---------------------------------------------------------------------------
__global__ void k_csr_a(const int* __restrict__ src, const int* __restrict__ dst,
                        int* __restrict__ bcur, unsigned* __restrict__ pairs) {
    __shared__ int hist[512];
    __shared__ int base[512];
    __shared__ int lcur[512];
    int t = threadIdx.x;            // 1024
    int blk = blockIdx.x;           // 256
    int e0 = blk * 8192;
    int bk[8]; unsigned p[8];
#pragma unroll
    for (int i = 0; i < 8; i++) {
        int e = e0 + i * 1024 + t;
        int d = dst[e];
        bk[i] = d >> 8;
        p[i] = ((unsigned)(d & 255) << 24) | (unsigned)src[e];
    }
    if (t < 512) hist[t] = 0;
    __syncthreads();
#pragma unroll
    for (int i = 0; i < 8; i++) atomicAdd(&hist[bk[i]], 1);
    __syncthreads();
    if (t < 512) {
        int h = hist[t];
        base[t] = h ? atomicAdd(&bcur[t], h) : 0;   // bucket-local base
        lcur[t] = 0;
    }
    __syncthreads();
#pragma unroll
    for (int i = 0; i < 8; i++) {
        int b = bk[i];
        int r = base[b] + atomicAdd(&lcur[b], 1);
        if (r < BCAP) pairs[(size_t)b * BCAP + r] = p[i];
    }
}

// Pass B: one workgroup per bucket. Per-node offsets + deg + csrc scatter +
// fused round-1 mean AND round-1 SAGE score (+ ghist pass-1 histogram).
__global__ void k_csr_b(const int* __restrict__ bcnt, const unsigned* __restrict__ pairs,
                        const float2* __restrict__ x2,
                        int* __restrict__ off, int* __restrict__ deg,
                        int* __restrict__ csrc, float2* __restrict__ mean,
                        const float* __restrict__ Wl1, const float* __restrict__ bl1,
                        const float* __restrict__ Wr1, const float* __restrict__ wp1,
                        const float* __restrict__ invn, float* __restrict__ score,
                        int* __restrict__ gh) {
    __shared__ int lcnt[256];
    __shared__ int lcur[256];
    __shared__ int wsum[4];
    int b = blockIdx.x, t = threadIdx.x;   // 512 blocks x 256
    int beg = b * BCAP;
    int c0 = bcnt[b]; if (c0 > BCAP) c0 = BCAP;
    int end = beg + c0;
    lcnt[t] = 0;
    __syncthreads();
    for (int i = beg + t; i < end; i += 256)
        atomicAdd(&lcnt[pairs[i] >> 24], 1);
    __syncthreads();
    int v = lcnt[t];
    int lane = t & 63, wv = t >> 6;
    int val = v;
    for (int o = 1; o < 64; o <<= 1) {
        int u = __shfl_up(val, o);
        if (lane >= o) val += u;
    }
    if (lane == 63) wsum[wv] = val;
    __syncthreads();
    int add = 0;
    for (int q = 0; q < wv; q++) add += wsum[q];
    int gpos = beg + val + add - v;        // exclusive within bucket, global
    off[b * 256 + t] = gpos;
    deg[b * 256 + t] = v;
    lcur[t] = gpos;
    __syncthreads();
    for (int i = beg + t; i < end; i += 256) {
        unsigned p = pairs[i];
        int pos = atomicAdd(&lcur[p >> 24], 1);
        csrc[pos] = (int)(p & 0x00FFFFFFu);
    }
    __syncthreads();   // drain csrc writes (vmcnt 0) before same-block re-read
    // fused round-1 mean: thread t owns node b*256+t, slice [gpos, gpos+v)
    float s0 = 0.f, s1 = 0.f;
    for (int e = gpos; e < gpos + v; e++) {
        float2 xv = x2[csrc[e]];
        s0 += xv.x; s1 += xv.y;
    }
    float c = fmaxf((float)v, 1.0f);
    float m0 = s0 / c, m1 = s1 / c;
    int n = b * 256 + t;
    mean[n] = make_float2(m0, m1);
    // fused round-1 score: serial 64-dim loop (weights broadcast, L2-hot)
    float2 xn = x2[n];
    float dacc = 0.f;
    for (int jj = 0; jj < 64; jj++) {
        float2 wl = ((const float2*)Wl1)[jj];
        float2 wr = ((const float2*)Wr1)[jj];
        float fv = wl.x * m0 + wl.y * m1 + bl1[jj] + wr.x * xn.x + wr.y * xn.y;
        fv = fmaxf(fv, 0.f);
        dacc += fv * wp1[jj];
    }
    float s = dacc * invn[0];
    score[n] = s;
    atomicAdd(&gh[(n >> 14) * 256 + (mono_key(s) >> 24)], 1);
}

// ---------------------------------------------------------------------------
// lin worker: ONE 64-reg weight column set per wave, 4-chain accumulator ILP.
// ---------------------------------------------------------------------------
__device__ __forceinline__
void lin_rows(const float* __restrict__ h, const float* __restrict__ WT,
              const float* __restrict__ bias, float* __restrict__ o,
              int Nn, int nblk, int blk0) {
    int j = threadIdx.x & 63, wv = threadIdx.x >> 6;
    float wreg[64];
#pragma unroll
    for (int q = 0; q < 64; q++) wreg[q] = WT[q * 64 + j];
    float bj = bias ? bias[j] : 0.f;
    int stride = nblk * 4;
    for (int n = blk0 * 4 + wv; n < Nn; n += stride) {
        float iv = h[(size_t)n * 64 + j];      // coalesced 256B row load
        float a0 = 0.f, a1 = 0.f, a2 = 0.f, a3 = 0.f;
#pragma unroll
        for (int q = 0; q < 16; q++) {
            float s0 = __int_as_float(__builtin_amdgcn_readlane(__float_as_int(iv), q));
            float s1 = __int_as_float(__builtin_amdgcn_readlane(__float_as_int(iv), q + 16));
            float s2 = __int_as_float(__builtin_amdgcn_readlane(__float_as_int(iv), q + 32));
            float s3 = __int_as_float(__builtin_amdgcn_readlane(__float_as_int(iv), q + 48));
            a0 += s0 * wreg[q];
            a1 += s1 * wreg[q + 16];
            a2 += s2 * wreg[q + 32];
            a3 += s3 * wreg[q + 48];
        }
        o[(size_t)n * 64 + j] = (a0 + a1) + (a2 + a3) + bj;
    }
}

// ---------------------------------------------------------------------------
// Fused per-round producer kernel (lin / lin2 / dis sections).
// ---------------------------------------------------------------------------
__global__ __launch_bounds__(256, 4)
void k_linf(const float* __restrict__ h,
            const float* __restrict__ WT1, float* __restrict__ o1, int linB1,
            const float* __restrict__ WT2, const float* __restrict__ bias,
            float* __restrict__ o2, int linB2,
            int Nn,
            const int* __restrict__ off, const int* __restrict__ deg,
            const int* __restrict__ csrc,
            const int* __restrict__ map, const int* __restrict__ orig,
            float* __restrict__ dis, int ng) {
    int blk = blockIdx.x;
    if (blk < linB1) {
        lin_rows(h, WT1, nullptr, o1, Nn, linB1, blk);
    } else if (blk < linB1 + linB2) {
        lin_rows(h, WT2, bias, o2, Nn, linB2, blk - linB1);
    } else {
        int b2 = blk - linB1 - linB2;
        int g = b2 & 7, i = b2 >> 3;
        int wv = threadIdx.x >> 6, j = threadIdx.x & 63;
        int n = g * ng + i * 4 + wv;
        int o = orig[n];
        int beg = off[o], end = beg + deg[o];
        int c = 0;
        for (int base = beg; base < end; base += 64) {
            int d = end - base; if (d > 64) d = 64;
            int cs = (j < d) ? map[csrc[base + j]] : -1;
            c += __popcll(__ballot(cs >= 0));
        }
        if (j == 0) dis[n] = 1.0f / sqrtf(1.0f + (float)c);
    }
}

// ---------------------------------------------------------------------------
// Per-graph top-k radix select. Pass-1 histogram PRECOMPUTED chip-wide into
// ghist by the score producers; passes 2-4 use per-wave private LDS hists,
// with whist zeroing overlapped into the scan phase (threads >= 64).
// Fused orig compose (og: 0 none, 1 identity, 2 compose through orig_in).
// ---------------------------------------------------------------------------
template<int M>
__global__ void k_topk(float* __restrict__ score, int* __restrict__ newpos,
                       int* __restrict__ perm,
                       const int* __restrict__ orig_in, int* __restrict__ orig_out,
                       int og, const int* __restrict__ ghist) {
    constexpr int n = M * 1024;
    constexpr int k = n / 2;
    __shared__ int whist[16][256];       // per-wave private histograms
    __shared__ unsigned hist[256];       // reduced histogram
    __shared__ unsigned sh_pfx, sh_msk, sh_rem;
    __shared__ int sh_eqtot, sh_ctr;
    __shared__ int wtot[16];
    __shared__ int runTie, runGt;
    int t = threadIdx.x, b = blockIdx.x;
    int base = b * n;
    int lane = t & 63, wv = t >> 6;

    unsigned kr[M];
#pragma unroll
    for (int i = 0; i < M; i++)
        kr[i] = mono_key(score[base + t + (i << 10)]);
    if (t == 0) { sh_pfx = 0; sh_msk = 0; sh_rem = (unsigned)k;
                  sh_eqtot = 0; sh_ctr = 0; runTie = 0; runGt = 0; }
    if (t < 256) hist[t] = (unsigned)ghist[b * 256 + t];   // precomputed pass 1
    ((int*)whist)[t] = 0; ((int*)whist)[t + 1024] = 0;     // zero for pass 2
    ((int*)whist)[t + 2048] = 0; ((int*)whist)[t + 3072] = 0;
    __syncthreads();
    // pass-1 scan (shift=24) directly on precomputed hist
    if (t < 64) {
        unsigned rem = sh_rem;
        unsigned c0 = hist[255 - (t * 4 + 0)];
        unsigned c1 = hist[255 - (t * 4 + 1)];
        unsigned c2 = hist[255 - (t * 4 + 2)];
        unsigned c3 = hist[255 - (t * 4 + 3)];
        unsigned s = c0 + c1 + c2 + c3;
        unsigned sc = s;
        for (int o = 1; o < 64; o <<= 1) {
            unsigned u = __shfl_up(sc, o);
            if (t >= o) sc += u;
        }
        unsigned run = sc - s;
        unsigned cc[4] = {c0, c1, c2, c3};
#pragma unroll
        for (int q = 0; q < 4; q++) {
            unsigned incl = run + cc[q];
            if (run < rem && incl >= rem) {
                int bb = 255 - (t * 4 + q);
                sh_rem = rem - run;
                sh_pfx = (unsigned)bb << 24;
                sh_msk = 255u << 24;
            }
            run = incl;
        }
    }
    __syncthreads();

    for (int shift = 16; shift >= 0; shift -= 8) {
        unsigned pfx = sh_pfx, msk = sh_msk;
#pragma unroll
        for (int i = 0; i < M; i++)
            if ((kr[i] & msk) == pfx) atomicAdd(&whist[wv][(kr[i] >> shift) & 255], 1);
        __syncthreads();
        if (t < 256) {
            int s = 0;
#pragma unroll
            for (int q = 0; q < 16; q++) s += whist[q][t];
            hist[t] = (unsigned)s;
        }
        __syncthreads();
        if (t < 64) {
            unsigned rem = sh_rem;
            unsigned c0 = hist[255 - (t * 4 + 0)];
            unsigned c1 = hist[255 - (t * 4 + 1)];
            unsigned c2 = hist[255 - (t * 4 + 2)];
            unsigned c3 = hist[255 - (t * 4 + 3)];
            unsigned s = c0 + c1 + c2 + c3;
            unsigned sc = s;
            for (int o = 1; o < 64; o <<= 1) {
                unsigned u = __shfl_up(sc, o);
                if (t >= o) sc += u;
            }
            unsigned run = sc - s;
            unsigned cc[4] = {c0, c1, c2, c3};
#pragma unroll
            for (int q = 0; q < 4; q++) {
                unsigned incl = run + cc[q];
                if (run < rem && incl >= rem) {
                    int bb = 255 - (t * 4 + q);
                    sh_rem = rem - run;
                    sh_pfx = pfx | ((unsigned)bb << shift);
                    sh_msk = msk | (255u << shift);
                }
                run = incl;
            }
        } else {
            // zero whist for next pass concurrently with the scan
            for (int z = t - 64; z < 4096; z += 960) ((int*)whist)[z] = 0;
        }
        __syncthreads();
    }
    unsigned K = sh_pfx;
    int T = (int)sh_rem;

    int le = 0;
#pragma unroll
    for (int i = 0; i < M; i++) le += (kr[i] == K) ? 1 : 0;
    for (int o = 32; o; o >>= 1) le += __shfl_xor(le, o);
    if (lane == 0) atomicAdd(&sh_eqtot, le);
    __syncthreads();

    if (sh_eqtot == T) {
        // fast path: every tie kept; order-free atomic compaction
#pragma unroll
        for (int i = 0; i < M; i++) {
            int cur = base + t + (i << 10);
            bool kept = kr[i] >= K;
            unsigned long long mk = __ballot(kept);
            int pos = 0;
            if (mk) {
                int fl = __ffsll(mk) - 1;
                int bp = 0;
                if (lane == fl) bp = atomicAdd(&sh_ctr, __popcll(mk));
                bp = __shfl(bp, fl);
                pos = bp + __popcll(mk & ((1ull << lane) - 1ull));
            }
            if (kept && pos < k) {
                newpos[cur] = b * k + pos;
                perm[b * k + pos] = cur;
                if (og) orig_out[b * k + pos] = (og == 1) ? cur : orig_in[cur];
                unsigned ob = (kr[i] & 0x80000000u) ? (kr[i] ^ 0x80000000u) : ~kr[i];
                score[cur] = tanhf(__uint_as_float(ob));
            } else newpos[cur] = -1;
        }
    } else {
        // ordered fallback (rare)
        for (int i = 0; i < M; i++) {
            unsigned key = kr[i];
            int gt = key > K ? 1 : 0;
            int eq = key == K ? 1 : 0;
            int val = (eq << 16) | gt;
            for (int o = 1; o < 64; o <<= 1) {
                int v = __shfl_up(val, o);
                if (lane >= o) val += v;
            }
            if (lane == 63) wtot[wv] = val;
            __syncthreads();
            int add = 0;
            for (int q = 0; q < 16; q++) if (q < wv) add += wtot[q];
            val += add;
            int eqIncl = val >> 16, gtIncl = val & 0xffff;
            int eqExcl = eqIncl - eq, gtExcl = gtIncl - gt;
            int kept = gt | (eq & ((runTie + eqExcl) < T ? 1 : 0));
            int cur = base + t + (i << 10);
            if (kept) {
                int selEqBefore = runTie + eqExcl; if (selEqBefore > T) selEqBefore = T;
                int nl = runGt + gtExcl + selEqBefore;
                if (nl < k) {
                    newpos[cur] = b * k + nl;
                    perm[b * k + nl] = cur;
                    if (og) orig_out[b * k + nl] = (og == 1) ? cur : orig_in[cur];
                    unsigned ob = (key & 0x80000000u) ? (key ^ 0x80000000u) : ~key;
                    score[cur] = tanhf(__uint_as_float(ob));
                } else newpos[cur] = -1;
            } else newpos[cur] = -1;
            __syncthreads();
            if (t == 1023) { runTie += eqIncl; runGt += gtIncl; }
            __syncthreads();
        }
    }
}

// gather kept rows gated by (tanh'd) score + fused per-block readout partials
// + fused map update section (blocks >= mainB; full-grid parallel).
__global__ void k_compact4(const float* __restrict__ hin, const float* __restrict__ score,
                           const int* __restrict__ perm, float* __restrict__ hout, int k,
                           float* __restrict__ partial,
                           const int* __restrict__ newpos, int* __restrict__ map,
                           int mode, int mainB) {
    __shared__ float sred[2][16][64];
    int blk = blockIdx.x;
    int t = threadIdx.x;
    if (blk >= mainB) {
        int gi = (blk - mainB) * 256 + t;
        if (mode == 1) map[gi] = newpos[gi];
        else { int m = map[gi]; map[gi] = (m >= 0) ? newpos[m] : -1; }
        return;
    }
    int g = blk & 7, i = blk >> 3;
    int r = t >> 4, c = t & 15;          // 16 rows x 16 float4 cols
    int nn = g * k + i * 16 + r;
    int old = perm[nn];
    float4 v = ((const float4*)(hin + (size_t)old * 64))[c];
    float sc = score[old];
    v.x *= sc; v.y *= sc; v.z *= sc; v.w *= sc;
    ((float4*)(hout + (size_t)nn * 64))[c] = v;
    sred[0][r][c * 4 + 0] = v.x; sred[0][r][c * 4 + 1] = v.y;
    sred[0][r][c * 4 + 2] = v.z; sred[0][r][c * 4 + 3] = v.w;
    sred[1][r][c * 4 + 0] = v.x; sred[1][r][c * 4 + 1] = v.y;
    sred[1][r][c * 4 + 2] = v.z; sred[1][r][c * 4 + 3] = v.w;
    __syncthreads();
    if (t < 64) {
        float mx = sred[0][0][t], sm = sred[1][0][t];
        for (int rr = 1; rr < 16; rr++) {
            mx = fmaxf(mx, sred[0][rr][t]);
            sm += sred[1][rr][t];
        }
        partial[(size_t)blk * 128 + t] = mx;
        partial[(size_t)blk * 128 + 64 + t] = sm;
    }
}

// Round-1 compact: RECOMPUTES the SAGE1 feature row from mean/x + weights
// (hA never materialized) + fused map section.
__global__ void k_compact4r(const float2* __restrict__ mean, const float2* __restrict__ x2,
                            const float* __restrict__ Wl1, const float* __restrict__ bl1,
                            const float* __restrict__ Wr1,
                            const float* __restrict__ score,
                            const int* __restrict__ perm, float* __restrict__ hout, int k,
                            float* __restrict__ partial,
                            const int* __restrict__ newpos, int* __restrict__ map,
                            int mode, int mainB) {
    __shared__ float sred[2][16][64];
    int blk = blockIdx.x;
    int t = threadIdx.x;
    if (blk >= mainB) {
        int gi = (blk - mainB) * 256 + t;
        if (mode == 1) map[gi] = newpos[gi];
        else { int m = map[gi]; map[gi] = (m >= 0) ? newpos[m] : -1; }
        return;
    }
    int g = blk & 7, i = blk >> 3;
    int r = t >> 4, c = t & 15;          // 16 rows x 16 float4 cols
    int nn = g * k + i * 16 + r;
    int old = perm[nn];
    float2 m = mean[old];
    float2 xn = x2[old];
    float4 wl01 = ((const float4*)Wl1)[c * 2];      // (Wl[4c].x,.y, Wl[4c+1].x,.y)
    float4 wl23 = ((const float4*)Wl1)[c * 2 + 1];
    float4 wr01 = ((const float4*)Wr1)[c * 2];
    float4 wr23 = ((const float4*)Wr1)[c * 2 + 1];
    float4 bl   = ((const float4*)bl1)[c];
    float4 v;
    v.x = fmaxf(wl01.x * m.x + wl01.y * m.y + bl.x + wr01.x * xn.x + wr01.y * xn.y, 0.f);
    v.y = fmaxf(wl01.z * m.x + wl01.w * m.y + bl.y + wr01.z * xn.x + wr01.w * xn.y, 0.f);
    v.z = fmaxf(wl23.x * m.x + wl23.y * m.y + bl.z + wr23.x * xn.x + wr23.y * xn.y, 0.f);
    v.w = fmaxf(wl23.z * m.x + wl23.w * m.y + bl.w + wr23.z * xn.x + wr23.w * xn.y, 0.f);
    float sc = score[old];
    v.x *= sc; v.y *= sc; v.z *= sc; v.w *= sc;
    ((float4*)(hout + (size_t)nn * 64))[c] = v;
    sred[0][r][c * 4 + 0] = v.x; sred[0][r][c * 4 + 1] = v.y;
    sred[0][r][c * 4 + 2] = v.z; sred[0][r][c * 4 + 3] = v.w;
    sred[1][r][c * 4 + 0] = v.x; sred[1][r][c * 4 + 1] = v.y;
    sred[1][r][c * 4 + 2] = v.z; sred[1][r][c * 4 + 3] = v.w;
    __syncthreads();
    if (t < 64) {
        float mx = sred[0][0][t], sm = sred[1][0][t];
        for (int rr = 1; rr < 16; rr++) {
            mx = fmaxf(mx, sred[0][rr][t]);
            sm += sred[1][rr][t];
        }
        partial[(size_t)blk * 128 + t] = mx;
        partial[(size_t)blk * 128 + 64 + t] = sm;
    }
}

// ---------------------------------------------------------------------------
// SAGE round 2, transform-first, float4-vectorized gather (+ ghist fill).
// ---------------------------------------------------------------------------
__global__ void k_sage_gather2(const float* __restrict__ gl, const int* __restrict__ off,
                               const int* __restrict__ deg, const int* __restrict__ csrc,
                               const int* __restrict__ map,
                               const int* __restrict__ orig, const float* __restrict__ wp,
                               const float* __restrict__ invn,
                               float* __restrict__ own_in,
                               float* __restrict__ out, float* __restrict__ score, int ng,
                               int* __restrict__ gh) {
    int blk = blockIdx.x;
    int g = blk & 7, i = blk >> 3;
    int wv = threadIdx.x >> 6, l = threadIdx.x & 63;
    int n = g * ng + i * 4 + wv;
    int o = orig[n];
    int beg = off[o], end = beg + deg[o];
    int fg = l & 15, es = l >> 4;
    float4 own = make_float4(0.f, 0.f, 0.f, 0.f);
    if (es == 0) own = ((const float4*)(own_in + (size_t)n * 64))[fg];
    float4 acc = make_float4(0.f, 0.f, 0.f, 0.f);
    int cnt = 0;
    for (int base = beg; base < end; base += 64) {
        int d = end - base; if (d > 64) d = 64;
        int cs = (l < d) ? map[csrc[base + l]] : -1;
        cnt += __popcll(__ballot(cs >= 0));
        for (int e = 0; e < d; e += 4) {
            int c = __shfl(cs, e + es);
            if (c >= 0) {
                float4 v = ((const float4*)(gl + (size_t)c * 64))[fg];
                acc.x += v.x; acc.y += v.y; acc.z += v.z; acc.w += v.w;
            }
        }
    }
    acc.x += __shfl_xor(acc.x, 16); acc.y += __shfl_xor(acc.y, 16);
    acc.z += __shfl_xor(acc.z, 16); acc.w += __shfl_xor(acc.w, 16);
    acc.x += __shfl_xor(acc.x, 32); acc.y += __shfl_xor(acc.y, 32);
    acc.z += __shfl_xor(acc.z, 32); acc.w += __shfl_xor(acc.w, 32);
    float c = fmaxf((float)cnt, 1.0f);
    float4 v;
    v.x = fmaxf(acc.x / c + own.x, 0.f);
    v.y = fmaxf(acc.y / c + own.y, 0.f);
    v.z = fmaxf(acc.z / c + own.z, 0.f);
    v.w = fmaxf(acc.w / c + own.w, 0.f);
    float dsc = 0.f;
    if (es == 0) {
        ((float4*)(out + (size_t)n * 64))[fg] = v;
        float4 w4 = ((const float4*)wp)[fg];
        dsc = v.x * w4.x + v.y * w4.y + v.z * w4.z + v.w * w4.w;
    }
    for (int o2 = 32; o2; o2 >>= 1) dsc += __shfl_xor(dsc, o2);
    if (l == 0) {
        float s = dsc * invn[0];
        score[n] = s;
        atomicAdd(&gh[g * 256 + (mono_key(s) >> 24)], 1);
    }
}

// GCN gather, float4-vectorized (+ ghist fill).
__global__ void k_gcn_gather(const float* __restrict__ xw, const int* __restrict__ off,
                             const int* __restrict__ deg, const int* __restrict__ csrc,
                             const int* __restrict__ map,
                             const int* __restrict__ orig, const float* __restrict__ dis,
                             const float* __restrict__ bb, const float* __restrict__ wp,
                             const float* __restrict__ invn,
                             float* __restrict__ out, float* __restrict__ score, int ng,
                             int* __restrict__ gh) {
    int blk = blockIdx.x;
    int g = blk & 7, i = blk >> 3;
    int wv = threadIdx.x >> 6, l = threadIdx.x & 63;
    int n = g * ng + i * 4 + wv;
    int o = orig[n];
    int beg = off[o], end = beg + deg[o];
    int fg = l & 15, es = l >> 4;
    float dn = dis[n];
    float4 own = make_float4(0.f, 0.f, 0.f, 0.f);
    if (es == 0) own = ((const float4*)(xw + (size_t)n * 64))[fg];
    float4 acc = make_float4(0.f, 0.f, 0.f, 0.f);
    for (int base = beg; base < end; base += 64) {
        int d = end - base; if (d > 64) d = 64;
        int cs = -1; float dsv = 0.f;
        if (l < d) {
            int cc = map[csrc[base + l]];
            if (cc >= 0) { cs = cc; dsv = dis[cc]; }
        }
        for (int e = 0; e < d; e += 4) {
            int c = __shfl(cs, e + es);
            float dv = __shfl(dsv, e + es);
            if (c >= 0) {
                float4 v = ((const float4*)(xw + (size_t)c * 64))[fg];
                acc.x += v.x * dv; acc.y += v.y * dv;
                acc.z += v.z * dv; acc.w += v.w * dv;
            }
        }
    }
    acc.x += __shfl_xor(acc.x, 16); acc.y += __shfl_xor(acc.y, 16);
    acc.z += __shfl_xor(acc.z, 16); acc.w += __shfl_xor(acc.w, 16);
    acc.x += __shfl_xor(acc.x, 32); acc.y += __shfl_xor(acc.y, 32);
    acc.z += __shfl_xor(acc.z, 32); acc.w += __shfl_xor(acc.w, 32);
    float dsc = 0.f;
    if (es == 0) {
        float4 b4 = ((const float4*)bb)[fg];
        float dd = dn * dn;
        float4 v;
        v.x = fmaxf(acc.x * dn + own.x * dd + b4.x, 0.f);
        v.y = fmaxf(acc.y * dn + own.y * dd + b4.y, 0.f);
        v.z = fmaxf(acc.z * dn + own.z * dd + b4.z, 0.f);
        v.w = fmaxf(acc.w * dn + own.w * dd + b4.w, 0.f);
        ((float4*)(out + (size_t)n * 64))[fg] = v;
        float4 w4 = ((const float4*)wp)[fg];
        dsc = v.x * w4.x + v.y * w4.y + v.z * w4.z + v.w * w4.w;
    }
    for (int o2 = 32; o2; o2 >>= 1) dsc += __shfl_xor(dsc, o2);
    if (l == 0) {
        float s = dsc * invn[0];
        score[n] = s;
        atomicAdd(&gh[g * 256 + (mono_key(s) >> 24)], 1);
    }
}

// ---------------------------------------------------------------------------
// Parallel partial reduction: 960 part-blocks/graph in 16 slices of 60.
// ---------------------------------------------------------------------------
__global__ void k_zred(const float* __restrict__ part, float* __restrict__ red2) {
    __shared__ float sred[2][128];
    int b2 = blockIdx.x;
    int g = b2 & 7, slice = b2 >> 3;
    int t = threadIdx.x;
    int j = t & 127, h = t >> 7;          // 2 half-slices of 30
    int pb0 = slice * 60 + h * 30;
    float accm = -3.0e38f, accs = 0.f;
    for (int pb = pb0; pb < pb0 + 30; pb++) {
        const float* p; int i; float scale;
        if (pb < 512)      { p = part + P1; i = pb;       scale = 1.0f / 8192.0f; }
        else if (pb < 768) { p = part + P2; i = pb - 512; scale = 1.0f / 4096.0f; }
        else if (pb < 896) { p = part + P3; i = pb - 768; scale = 1.0f / 2048.0f; }
        else               { p = part + P4; i = pb - 896; scale = 1.0f / 1024.0f; }
        float v = p[(size_t)(i * 8 + g) * 128 + j];
        accm = fmaxf(accm, v);
        accs += v * scale;
    }
    sred[h][j] = (j < 64) ? accm : accs;
    __syncthreads();
    if (t < 128) {
        float out = (j < 64) ? fmaxf(sred[0][j], sred[1][j]) : (sred[0][j] + sred[1][j]);
        red2[(size_t)b2 * 128 + j] = out;
    }
}

// ---------------------------------------------------------------------------
// Fused z assembly (from red2) + MLP + softmax. 8 blocks x 1024 threads.
// ---------------------------------------------------------------------------
__global__ void k_mlpz(const float* __restrict__ red2,
                       const float* __restrict__ WaT, const float* __restrict__ ba,
                       const float* __restrict__ WbT, const float* __restrict__ bb,
                       const float* __restrict__ WcT, const float* __restrict__ bc,
                       float* __restrict__ out) {
    __shared__ float red[8][128];
    __shared__ float sz[128];
    __shared__ float sa[128];
    __shared__ float sb2[64];
    __shared__ float sc[256];
    __shared__ float tmp[256];
    __shared__ float wred[4];
    int b = blockIdx.x, t = threadIdx.x;
    int j = t & 127, s = t >> 7;           // s in 0..7; 2 slices each
    {
        float v0 = red2[(size_t)((s * 2 + 0) * 8 + b) * 128 + j];
        float v1 = red2[(size_t)((s * 2 + 1) * 8 + b) * 128 + j];
        red[s][j] = (j < 64) ? fmaxf(v0, v1) : (v0 + v1);
    }
    __syncthreads();
    if (t < 128) {
        float zv;
        if (j < 64) {
            float m1 = fmaxf(fmaxf(red[0][j], red[1][j]), fmaxf(red[2][j], red[3][j]));
            float m2 = fmaxf(fmaxf(red[4][j], red[5][j]), fmaxf(red[6][j], red[7][j]));
            zv = fmaxf(m1, m2);
        } else {
            zv = ((red[0][j] + red[1][j]) + (red[2][j] + red[3][j]))
               + ((red[4][j] + red[5][j]) + (red[6][j] + red[7][j]));
        }
        sz[t] = zv;
    }
    __syncthreads();
    if (t < 256) {
        int o = t & 127, half = t >> 7;
        float v = 0.f;
        int q0 = half * 64;
        for (int q = q0; q < q0 + 64; q++) v += sz[q] * WaT[q * 128 + o];
        tmp[t] = v;
    }
    __syncthreads();
    if (t < 128) sa[t] = fmaxf(tmp[t] + tmp[t + 128] + ba[t], 0.f);
    __syncthreads();
    if (t < 256) {
        int o = t & 63, qr = t >> 6;
        float v = 0.f;
        int q0 = qr * 32;
        for (int q = q0; q < q0 + 32; q++) v += sa[q] * WbT[q * 64 + o];
        tmp[t] = v;
    }
    __syncthreads();
    if (t < 64) sb2[t] = fmaxf(tmp[t] + tmp[t + 64] + tmp[t + 128] + tmp[t + 192] + bb[t], 0.f);
    __syncthreads();
    if (t < 256) {
        float v = bc[t];
        for (int q = 0; q < 64; q++) v += sb2[q] * WcT[q * 256 + t];
        sc[t] = v;
    }
    __syncthreads();
    if (t < 256) {
        float m = sc[t];
        for (int o2 = 32; o2; o2 >>= 1) m = fmaxf(m, __shfl_xor(m, o2));
        if ((t & 63) == 0) wred[t >> 6] = m;
    }
    __syncthreads();
    float m = fmaxf(fmaxf(wred[0], wred[1]), fmaxf(wred[2], wred[3]));
    __syncthreads();
    if (t < 256) {
        float e = expf(sc[t] - m);
        tmp[t] = e;
        float ss = e;
        for (int o2 = 32; o2; o2 >>= 1) ss += __shfl_xor(ss, o2);
        if ((t & 63) == 0) wred[t >> 6] = ss;
    }
    __syncthreads();
    if (t < 256) {
        float ss = wred[0] + wred[1] + wred[2] + wred[3];
        out[b * 256 + t] = tmp[t] / ss;
    }
}

// ---------------------------------------------------------------------------
extern "C" void kernel_launch(void* const* d_in, const int* in_sizes, int n_in,
                              void* d_out, int out_size, void* d_ws, size_t ws_size,
                              hipStream_t stream) {
    const float* x   = (const float*)d_in[0];
    const int*   ei  = (const int*)d_in[1];
    const int* src = ei;
    const int* dst = ei + Eq;
    const float* Wl1 = (const float*)d_in[2];
    const float* bl1 = (const float*)d_in[3];
    const float* Wr1 = (const float*)d_in[4];
    const float* Wl2 = (const float*)d_in[5];
    const float* bl2 = (const float*)d_in[6];
    const float* Wr2 = (const float*)d_in[7];
    const float* W4  = (const float*)d_in[8];
    const float* b4  = (const float*)d_in[9];
    const float* W5  = (const float*)d_in[10];
    const float* b5  = (const float*)d_in[11];
    const float* wp1 = (const float*)d_in[12];
    const float* wp2 = (const float*)d_in[13];
    const float* wp4 = (const float*)d_in[14];
    const float* wp5 = (const float*)d_in[15];
    const float* Wa  = (const float*)d_in[16];
    const float* ba  = (const float*)d_in[17];
    const float* Wb  = (const float*)d_in[18];
    const float* bbv = (const float*)d_in[19];
    const float* Wc  = (const float*)d_in[20];
    const float* bc  = (const float*)d_in[21];
    float* out = (float*)d_out;

    const int N1 = Nq / 2, N2 = Nq / 4, N3 = Nq / 8, N4 = Nq / 16;

    // workspace layout
    char* w = (char*)d_ws;
    float* hA    = (float*)w; w += (size_t)Nq * 64 * 4;        // 33.5 MB
    float* hB    = (float*)w; w += (size_t)N1 * 64 * 4;        // 16.8 MB (pooled rows)
    float* hC    = (float*)w; w += (size_t)N1 * 64 * 4;        // 16.8 MB (gl / xw)
    int*   csrc  = (int*)w;   w += (size_t)512 * BCAP * 4;     // 16.8 MB (bucketed)
    int*   coff  = (int*)w;   w += (size_t)(Nq + 1) * 4;
    int*   degA  = (int*)w;   w += (size_t)Nq * 4;             // per-node degree
    int*   bcur  = (int*)w;   w += (size_t)Nq * 4;             // 512 used; winv in tail
    int*   cnt   = (int*)w;   w += (size_t)Nq * 4;             // aliased by mean (lo)
    float* dis   = (float*)w; w += (size_t)Nq * 4;             // aliased by mean (hi)
    float* score = (float*)w; w += (size_t)Nq * 4;
    int*   newpos= (int*)w;   w += (size_t)Nq * 4;
    int*   map   = (int*)w;   w += (size_t)Nq * 4;
    int*   perm  = (int*)w;   w += (size_t)Nq * 4;
    int*   origA = (int*)w;   w += (size_t)Nq * 4;
    int*   origB = (int*)w;   w += (size_t)Nq * 4;
    float* part  = (float*)w; w += (size_t)PTOT * 4;           // 3.93 MB partials
    float* red2  = (float*)w; w += (size_t)128 * 128 * 4;      // 64 KB slice partials
    int*   ghist = (int*)w;   w += (size_t)4 * 2048 * 4;       // 32 KB topk pass-1 hists
    float* wT    = (float*)w; w += 4 * 4096 * 4;               // 64 KB
    float* wMT   = (float*)w; w += (16384 + 8192 + 16384) * 4; // 160 KB
    float* WlT2 = wT, *WrT2 = wT + 4096, *W4T = wT + 8192, *W5T = wT + 12288;
    float* WaT = wMT, *WbT = wMT + 16384, *WcT = wMT + 16384 + 8192;
    unsigned* pairs = (unsigned*)hA;      // CSR staging aliases hA (free then)
    float2* mean = (float2*)cnt;          // Nq float2 spans cnt+dis (dis used later)
    float* winv = (float*)(bcur + 1024);  // 4 floats in free tail of bcur slot

    // ---- One-time: prep (transposes + wnorm + bcur/ghist zero) + CSR build
    // (k_csr_b also emits the round-1 mean, score AND pass-1 histogram)
    k_prep<<<8, 256, 0, stream>>>(Wl2, Wr2, W4, W5, Wa, Wb, Wc,
                                  wp1, wp2, wp4, wp5, wT, wMT, winv, bcur, ghist);
    k_csr_a<<<256, 1024, 0, stream>>>(src, dst, bcur, pairs);
    k_csr_b<<<512, 256, 0, stream>>>(bcur, pairs, (const float2*)x, coff, degA, csrc, mean,
                                     Wl1, bl1, Wr1, wp1, winv, score, ghist);

    // ---- Round 1: topk (pass-1 precomputed), compact-recompute(+partials+map)
    k_topk<16><<<8, 1024, 0, stream>>>(score, newpos, perm, nullptr, origA, 1, ghist);
    k_compact4r<<<4096 + 512, 256, 0, stream>>>(mean, (const float2*)x, Wl1, bl1, Wr1,
                                                score, perm, hB, N1 / 8, part + P1,
                                                newpos, map, 1, 4096);

    // ---- Round 2: fused [hB@Wl->hC | hB@Wr+bl->hA] then gather (+ghist)
    k_linf<<<512 + 512, 256, 0, stream>>>(hB,
                                          WlT2, hC, 512,
                                          WrT2, bl2, hA, 512,
                                          N1,
                                          nullptr, nullptr, nullptr, nullptr, nullptr,
                                          nullptr, 0);
    k_sage_gather2<<<N1 / 4, 256, 0, stream>>>(hC, coff, degA, csrc, map, origA,
                                               wp2, winv + 1, hA, hA, score, N1 / 8,
                                               ghist + 2048);
    k_topk<8><<<8, 1024, 0, stream>>>(score, newpos, perm, origA, origB, 2, ghist + 2048);
    k_compact4<<<2048 + 512, 256, 0, stream>>>(hA, score, perm, hB, N2 / 8, part + P2,
                                               newpos, map, 2, 2048);

    // ---- Round 3: fused [hB@W4->hC | dis] then gather (+ghist)
    k_linf<<<512 + 8192, 256, 0, stream>>>(hB,
                                           W4T, hC, 512,
                                           nullptr, nullptr, nullptr, 0,
                                           N2,
                                           coff, degA, csrc, map, origB,
                                           dis, N2 / 8);
    k_gcn_gather<<<N2 / 4, 256, 0, stream>>>(hC, coff, degA, csrc, map, origB, dis,
                                             b4, wp4, winv + 2, hA, score, N2 / 8,
                                             ghist + 4096);
    k_topk<4><<<8, 1024, 0, stream>>>(score, newpos, perm, origB, origA, 2, ghist + 4096);
    k_compact4<<<1024 + 512, 256, 0, stream>>>(hA, score, perm, hB, N3 / 8, part + P3,
                                               newpos, map, 2, 1024);

    // ---- Round 4: fused [hB@W5->hC | dis] then gather (+ghist)
    k_linf<<<256 + 4096, 256, 0, stream>>>(hB,
                                           W5T, hC, 256,
                                           nullptr, nullptr, nullptr, 0,
                                           N3,
                                           coff, degA, csrc, map, origA,
                                           dis, N3 / 8);
    k_gcn_gather<<<N3 / 4, 256, 0, stream>>>(hC, coff, degA, csrc, map, origA, dis,
                                             b5, wp5, winv + 3, hA, score, N3 / 8,
                                             ghist + 6144);
    k_topk<2><<<8, 1024, 0, stream>>>(score, newpos, perm, nullptr, nullptr, 0, ghist + 6144);
    k_compact4<<<512, 256, 0, stream>>>(hA, score, perm, hB, N4 / 8, part + P4,
                                        newpos, map, 0, 512);

    // ---- parallel z reduction, then MLP + softmax
    k_zred<<<128, 256, 0, stream>>>(part, red2);
    k_mlpz<<<8, 1024, 0, stream>>>(red2, WaT, ba, WbT, bbv, WcT, bc, out);
}

// Round 17
// 383.238 us; speedup vs baseline: 1.5870x; 1.5870x over previous
//
#include <hip/hip_runtime.h>
#include <math.h>

constexpr int Bq  = 8;
constexpr int NGq = 16384;
constexpr int Nq  = Bq * NGq;       // 131072 nodes
constexpr int Eq  = Nq * 16;        // 2097152 edges
constexpr int Eg  = Eq / 8;         // 262144 edges per graph
constexpr int BCAP = 8192;          // fixed bucket capacity (mean 4096, sd 64)

// partial-buffer float offsets (compact-fused readout partials)
constexpr int P1 = 0;               // 4096 blocks x 128
constexpr int P2 = 524288;          // 2048 x 128
constexpr int P3 = 786432;          // 1024 x 128
constexpr int P4 = 917504;          //  512 x 128
constexpr int PTOT = 983040;

// ---------------------------------------------------------------------------
// One-time prep: all weight transposes + wp norms + bcur zero. 8 blocks.
// ---------------------------------------------------------------------------
__global__ void k_prep(const float* __restrict__ Wl2, const float* __restrict__ Wr2,
                       const float* __restrict__ W4, const float* __restrict__ W5,
                       const float* __restrict__ Wa, const float* __restrict__ Wb,
                       const float* __restrict__ Wc,
                       const float* __restrict__ w1, const float* __restrict__ w2,
                       const float* __restrict__ w4p, const float* __restrict__ w5p,
                       float* __restrict__ wT, float* __restrict__ wMT,
                       float* __restrict__ winv, int* __restrict__ bcur) {
    int t = threadIdx.x, b = blockIdx.x;
    if (b < 4) {
        const float* in = (b == 0) ? Wl2 : (b == 1) ? Wr2 : (b == 2) ? W4 : W5;
        float* out = wT + (size_t)b * 4096;
        for (int i = t; i < 4096; i += 256) {
            int r = i >> 6, c = i & 63;
            out[c * 64 + r] = in[r * 64 + c];
        }
    } else if (b == 4) {
        float* WaT = wMT;
        for (int i = t; i < 16384; i += 256) {
            int r = i >> 7, c = i & 127;
            WaT[c * 128 + r] = Wa[r * 128 + c];
        }
    } else if (b == 5) {
        float* WbT = wMT + 16384;
        for (int i = t; i < 8192; i += 256) {
            int r = i >> 7, c = i & 127;
            WbT[c * 64 + r] = Wb[r * 128 + c];
        }
    } else if (b == 6) {
        float* WcT = wMT + 16384 + 8192;
        for (int i = t; i < 16384; i += 256) {
            int r = i >> 6, c = i & 63;
            WcT[c * 256 + r] = Wc[r * 64 + c];
        }
    } else {
        int vsel = t >> 6, lane = t & 63;
        const float* wp = (vsel == 0) ? w1 : (vsel == 1) ? w2 : (vsel == 2) ? w4p : w5p;
        float v = wp[lane];
        float ww = v * v;
        for (int o = 32; o; o >>= 1) ww += __shfl_xor(ww, o);
        if (lane == 0) winv[vsel] = 1.0f / sqrtf(ww);
        for (int i = t; i < 512; i += 256) bcur[i] = 0;
    }
}

// ---------------------------------------------------------------------------
// CSR build: fixed-capacity buckets (bucket = dst>>8, region b*BCAP).
// ---------------------------------------------------------------------------
__global__ void k_csr_a(const int* __restrict__ src, const int* __restrict__ dst,
                        int* __restrict__ bcur, unsigned* __restrict__ pairs) {
    __shared__ int hist[512];
    __shared__ int base[512];
    __shared__ int lcur[512];
    int t = threadIdx.x;            // 1024
    int blk = blockIdx.x;           // 256
    int e0 = blk * 8192;
    int bk[8]; unsigned p[8];
#pragma unroll
    for (int i = 0; i < 8; i++) {
        int e = e0 + i * 1024 + t;
        int d = dst[e];
        bk[i] = d >> 8;
        p[i] = ((unsigned)(d & 255) << 24) | (unsigned)src[e];
    }
    if (t < 512) hist[t] = 0;
    __syncthreads();
#pragma unroll
    for (int i = 0; i < 8; i++) atomicAdd(&hist[bk[i]], 1);
    __syncthreads();
    if (t < 512) {
        int h = hist[t];
        base[t] = h ? atomicAdd(&bcur[t], h) : 0;   // bucket-local base
        lcur[t] = 0;
    }
    __syncthreads();
#pragma unroll
    for (int i = 0; i < 8; i++) {
        int b = bk[i];
        int r = base[b] + atomicAdd(&lcur[b], 1);
        if (r < BCAP) pairs[(size_t)b * BCAP + r] = p[i];
    }
}

// Pass B: one workgroup per bucket. Per-node offsets + deg + csrc scatter +
// fused round-1 mean AND round-1 SAGE score (serial 64-dim loop over L2-hot
// weights; score stored PRE-tanh, tanh applied to kept nodes in k_topk).
__global__ void k_csr_b(const int* __restrict__ bcnt, const unsigned* __restrict__ pairs,
                        const float2* __restrict__ x2,
                        int* __restrict__ off, int* __restrict__ deg,
                        int* __restrict__ csrc, float2* __restrict__ mean,
                        const float* __restrict__ Wl1, const float* __restrict__ bl1,
                        const float* __restrict__ Wr1, const float* __restrict__ wp1,
                        const float* __restrict__ invn, float* __restrict__ score) {
    __shared__ int lcnt[256];
    __shared__ int lcur[256];
    __shared__ int wsum[4];
    int b = blockIdx.x, t = threadIdx.x;   // 512 blocks x 256
    int beg = b * BCAP;
    int c0 = bcnt[b]; if (c0 > BCAP) c0 = BCAP;
    int end = beg + c0;
    lcnt[t] = 0;
    __syncthreads();
    for (int i = beg + t; i < end; i += 256)
        atomicAdd(&lcnt[pairs[i] >> 24], 1);
    __syncthreads();
    int v = lcnt[t];
    int lane = t & 63, wv = t >> 6;
    int val = v;
    for (int o = 1; o < 64; o <<= 1) {
        int u = __shfl_up(val, o);
        if (lane >= o) val += u;
    }
    if (lane == 63) wsum[wv] = val;
    __syncthreads();
    int add = 0;
    for (int q = 0; q < wv; q++) add += wsum[q];
    int gpos = beg + val + add - v;        // exclusive within bucket, global
    off[b * 256 + t] = gpos;
    deg[b * 256 + t] = v;
    lcur[t] = gpos;
    __syncthreads();
    for (int i = beg + t; i < end; i += 256) {
        unsigned p = pairs[i];
        int pos = atomicAdd(&lcur[p >> 24], 1);
        csrc[pos] = (int)(p & 0x00FFFFFFu);
    }
    __syncthreads();   // drain csrc writes (vmcnt 0) before same-block re-read
    // fused round-1 mean: thread t owns node b*256+t, slice [gpos, gpos+v)
    float s0 = 0.f, s1 = 0.f;
    for (int e = gpos; e < gpos + v; e++) {
        float2 xv = x2[csrc[e]];
        s0 += xv.x; s1 += xv.y;
    }
    float c = fmaxf((float)v, 1.0f);
    float m0 = s0 / c, m1 = s1 / c;
    int n = b * 256 + t;
    mean[n] = make_float2(m0, m1);
    // fused round-1 score: serial 64-dim loop (weights broadcast, L2-hot)
    float2 xn = x2[n];
    float dacc = 0.f;
    for (int jj = 0; jj < 64; jj++) {
        float2 wl = ((const float2*)Wl1)[jj];
        float2 wr = ((const float2*)Wr1)[jj];
        float fv = wl.x * m0 + wl.y * m1 + bl1[jj] + wr.x * xn.x + wr.y * xn.y;
        fv = fmaxf(fv, 0.f);
        dacc += fv * wp1[jj];
    }
    score[n] = dacc * invn[0];
}

// ---------------------------------------------------------------------------
// lin worker: ONE 64-reg weight column set per wave, 4-chain accumulator ILP.
// ---------------------------------------------------------------------------
__device__ __forceinline__
void lin_rows(const float* __restrict__ h, const float* __restrict__ WT,
              const float* __restrict__ bias, float* __restrict__ o,
              int Nn, int nblk, int blk0) {
    int j = threadIdx.x & 63, wv = threadIdx.x >> 6;
    float wreg[64];
#pragma unroll
    for (int q = 0; q < 64; q++) wreg[q] = WT[q * 64 + j];
    float bj = bias ? bias[j] : 0.f;
    int stride = nblk * 4;
    for (int n = blk0 * 4 + wv; n < Nn; n += stride) {
        float iv = h[(size_t)n * 64 + j];      // coalesced 256B row load
        float a0 = 0.f, a1 = 0.f, a2 = 0.f, a3 = 0.f;
#pragma unroll
        for (int q = 0; q < 16; q++) {
            float s0 = __int_as_float(__builtin_amdgcn_readlane(__float_as_int(iv), q));
            float s1 = __int_as_float(__builtin_amdgcn_readlane(__float_as_int(iv), q + 16));
            float s2 = __int_as_float(__builtin_amdgcn_readlane(__float_as_int(iv), q + 32));
            float s3 = __int_as_float(__builtin_amdgcn_readlane(__float_as_int(iv), q + 48));
            a0 += s0 * wreg[q];
            a1 += s1 * wreg[q + 16];
            a2 += s2 * wreg[q + 32];
            a3 += s3 * wreg[q + 48];
        }
        o[(size_t)n * 64 + j] = (a0 + a1) + (a2 + a3) + bj;
    }
}

// ---------------------------------------------------------------------------
// Fused per-round producer kernel. Grid partitioned into
//   [0, linB1)            : lin h@WT1 -> o1
//   [linB1, linB1+linB2)  : lin h@WT2 + bias -> o2 (round 2 only)
//   [linB1+linB2, end)    : live-neighbor count -> dis (GCN rounds)
// ---------------------------------------------------------------------------
__global__ __launch_bounds__(256, 4)
void k_linf(const float* __restrict__ h,
            const float* __restrict__ WT1, float* __restrict__ o1, int linB1,
            const float* __restrict__ WT2, const float* __restrict__ bias,
            float* __restrict__ o2, int linB2,
            int Nn,
            const int* __restrict__ off, const int* __restrict__ deg,
            const int* __restrict__ csrc,
            const int* __restrict__ map, const int* __restrict__ orig,
            float* __restrict__ dis, int ng) {
    int blk = blockIdx.x;
    if (blk < linB1) {
        lin_rows(h, WT1, nullptr, o1, Nn, linB1, blk);
    } else if (blk < linB1 + linB2) {
        lin_rows(h, WT2, bias, o2, Nn, linB2, blk - linB1);
    } else {
        int b2 = blk - linB1 - linB2;
        int g = b2 & 7, i = b2 >> 3;
        int wv = threadIdx.x >> 6, j = threadIdx.x & 63;
        int n = g * ng + i * 4 + wv;
        int o = orig[n];
        int beg = off[o], end = beg + deg[o];
        int c = 0;
        for (int base = beg; base < end; base += 64) {
            int d = end - base; if (d > 64) d = 64;
            int cs = (j < d) ? map[csrc[base + j]] : -1;
            c += __popcll(__ballot(cs >= 0));
        }
        if (j == 0) dis[n] = 1.0f / sqrtf(1.0f + (float)c);
    }
}

// ---------------------------------------------------------------------------
// Per-graph top-k radix select (keys in registers) + fused orig compose
// (og: 0 none, 1 identity, 2 compose through orig_in). Map update in the
// following compact kernel. Pass histograms PER-WAVE PRIVATE (16x256 LDS).
// ---------------------------------------------------------------------------
template<int M>
__global__ void k_topk(float* __restrict__ score, int* __restrict__ newpos,
                       int* __restrict__ perm,
                       const int* __restrict__ orig_in, int* __restrict__ orig_out,
                       int og) {
    constexpr int n = M * 1024;
    constexpr int k = n / 2;
    __shared__ int whist[16][256];       // per-wave private histograms
    __shared__ unsigned hist[256];       // reduced histogram
    __shared__ unsigned sh_pfx, sh_msk, sh_rem;
    __shared__ int sh_eqtot, sh_ctr;
    __shared__ int wtot[16];
    __shared__ int runTie, runGt;
    int t = threadIdx.x, b = blockIdx.x;
    int base = b * n;
    int lane = t & 63, wv = t >> 6;

    unsigned kr[M];
#pragma unroll
    for (int i = 0; i < M; i++) {
        unsigned u = __float_as_uint(score[base + t + (i << 10)]);
        kr[i] = u ^ ((u >> 31) ? 0xFFFFFFFFu : 0x80000000u);
    }
    if (t == 0) { sh_pfx = 0; sh_msk = 0; sh_rem = (unsigned)k;
                  sh_eqtot = 0; sh_ctr = 0; runTie = 0; runGt = 0; }

    for (int shift = 24; shift >= 0; shift -= 8) {
        // zero per-wave hists (4096 ints, 4 per thread)
        ((int*)whist)[t] = 0; ((int*)whist)[t + 1024] = 0;
        ((int*)whist)[t + 2048] = 0; ((int*)whist)[t + 3072] = 0;
        __syncthreads();
        unsigned pfx = sh_pfx, msk = sh_msk;
#pragma unroll
        for (int i = 0; i < M; i++)
            if ((kr[i] & msk) == pfx) atomicAdd(&whist[wv][(kr[i] >> shift) & 255], 1);
        __syncthreads();
        if (t < 256) {
            int s = 0;
#pragma unroll
            for (int q = 0; q < 16; q++) s += whist[q][t];
            hist[t] = (unsigned)s;
        }
        __syncthreads();
        if (t < 64) {
            unsigned rem = sh_rem;
            unsigned c0 = hist[255 - (t * 4 + 0)];
            unsigned c1 = hist[255 - (t * 4 + 1)];
            unsigned c2 = hist[255 - (t * 4 + 2)];
            unsigned c3 = hist[255 - (t * 4 + 3)];
            unsigned s = c0 + c1 + c2 + c3;
            unsigned sc = s;
            for (int o = 1; o < 64; o <<= 1) {
                unsigned u = __shfl_up(sc, o);
                if (t >= o) sc += u;
            }
            unsigned run = sc - s;
            unsigned cc[4] = {c0, c1, c2, c3};
#pragma unroll
            for (int q = 0; q < 4; q++) {
                unsigned incl = run + cc[q];
                if (run < rem && incl >= rem) {
                    int bb = 255 - (t * 4 + q);
                    sh_rem = rem - run;
                    sh_pfx = pfx | ((unsigned)bb << shift);
                    sh_msk = msk | (255u << shift);
                }
                run = incl;
            }
        }
        __syncthreads();
    }
    unsigned K = sh_pfx;
    int T = (int)sh_rem;

    int le = 0;
#pragma unroll
    for (int i = 0; i < M; i++) le += (kr[i] == K) ? 1 : 0;
    for (int o = 32; o; o >>= 1) le += __shfl_xor(le, o);
    if (lane == 0) atomicAdd(&sh_eqtot, le);
    __syncthreads();

    if (sh_eqtot == T) {
        // fast path: every tie kept; order-free atomic compaction
#pragma unroll
        for (int i = 0; i < M; i++) {
            int cur = base + t + (i << 10);
            bool kept = kr[i] >= K;
            unsigned long long mk = __ballot(kept);
            int pos = 0;
            if (mk) {
                int fl = __ffsll(mk) - 1;
                int bp = 0;
                if (lane == fl) bp = atomicAdd(&sh_ctr, __popcll(mk));
                bp = __shfl(bp, fl);
                pos = bp + __popcll(mk & ((1ull << lane) - 1ull));
            }
            if (kept && pos < k) {
                newpos[cur] = b * k + pos;
                perm[b * k + pos] = cur;
                if (og) orig_out[b * k + pos] = (og == 1) ? cur : orig_in[cur];
                unsigned ob = (kr[i] & 0x80000000u) ? (kr[i] ^ 0x80000000u) : ~kr[i];
                score[cur] = tanhf(__uint_as_float(ob));
            } else newpos[cur] = -1;
        }
    } else {
        // ordered fallback (rare)
        for (int i = 0; i < M; i++) {
            unsigned key = kr[i];
            int gt = key > K ? 1 : 0;
            int eq = key == K ? 1 : 0;
            int val = (eq << 16) | gt;
            for (int o = 1; o < 64; o <<= 1) {
                int v = __shfl_up(val, o);
                if (lane >= o) val += v;
            }
            if (lane == 63) wtot[wv] = val;
            __syncthreads();
            int add = 0;
            for (int q = 0; q < 16; q++) if (q < wv) add += wtot[q];
            val += add;
            int eqIncl = val >> 16, gtIncl = val & 0xffff;
            int eqExcl = eqIncl - eq, gtExcl = gtIncl - gt;
            int kept = gt | (eq & ((runTie + eqExcl) < T ? 1 : 0));
            int cur = base + t + (i << 10);
            if (kept) {
                int selEqBefore = runTie + eqExcl; if (selEqBefore > T) selEqBefore = T;
                int nl = runGt + gtExcl + selEqBefore;
                if (nl < k) {
                    newpos[cur] = b * k + nl;
                    perm[b * k + nl] = cur;
                    if (og) orig_out[b * k + nl] = (og == 1) ? cur : orig_in[cur];
                    unsigned ob = (key & 0x80000000u) ? (key ^ 0x80000000u) : ~key;
                    score[cur] = tanhf(__uint_as_float(ob));
                } else newpos[cur] = -1;
            } else newpos[cur] = -1;
            __syncthreads();
            if (t == 1023) { runTie += eqIncl; runGt += gtIncl; }
            __syncthreads();
        }
    }
}

// gather kept rows gated by (tanh'd) score + fused per-block readout partials
// + fused map update section (blocks >= mainB; full-grid parallel).
__global__ void k_compact4(const float* __restrict__ hin, const float* __restrict__ score,
                           const int* __restrict__ perm, float* __restrict__ hout, int k,
                           float* __restrict__ partial,
                           const int* __restrict__ newpos, int* __restrict__ map,
                           int mode, int mainB) {
    __shared__ float sred[2][16][64];
    int blk = blockIdx.x;
    int t = threadIdx.x;
    if (blk >= mainB) {
        int gi = (blk - mainB) * 256 + t;
        if (mode == 1) map[gi] = newpos[gi];
        else { int m = map[gi]; map[gi] = (m >= 0) ? newpos[m] : -1; }
        return;
    }
    int g = blk & 7, i = blk >> 3;
    int r = t >> 4, c = t & 15;          // 16 rows x 16 float4 cols
    int nn = g * k + i * 16 + r;
    int old = perm[nn];
    float4 v = ((const float4*)(hin + (size_t)old * 64))[c];
    float sc = score[old];
    v.x *= sc; v.y *= sc; v.z *= sc; v.w *= sc;
    ((float4*)(hout + (size_t)nn * 64))[c] = v;
    sred[0][r][c * 4 + 0] = v.x; sred[0][r][c * 4 + 1] = v.y;
    sred[0][r][c * 4 + 2] = v.z; sred[0][r][c * 4 + 3] = v.w;
    sred[1][r][c * 4 + 0] = v.x; sred[1][r][c * 4 + 1] = v.y;
    sred[1][r][c * 4 + 2] = v.z; sred[1][r][c * 4 + 3] = v.w;
    __syncthreads();
    if (t < 64) {
        float mx = sred[0][0][t], sm = sred[1][0][t];
        for (int rr = 1; rr < 16; rr++) {
            mx = fmaxf(mx, sred[0][rr][t]);
            sm += sred[1][rr][t];
        }
        partial[(size_t)blk * 128 + t] = mx;
        partial[(size_t)blk * 128 + 64 + t] = sm;
    }
}

// Round-1 compact: RECOMPUTES the SAGE1 feature row from mean/x + weights
// (hA never materialized) + fused map section.
__global__ void k_compact4r(const float2* __restrict__ mean, const float2* __restrict__ x2,
                            const float* __restrict__ Wl1, const float* __restrict__ bl1,
                            const float* __restrict__ Wr1,
                            const float* __restrict__ score,
                            const int* __restrict__ perm, float* __restrict__ hout, int k,
                            float* __restrict__ partial,
                            const int* __restrict__ newpos, int* __restrict__ map,
                            int mode, int mainB) {
    __shared__ float sred[2][16][64];
    int blk = blockIdx.x;
    int t = threadIdx.x;
    if (blk >= mainB) {
        int gi = (blk - mainB) * 256 + t;
        if (mode == 1) map[gi] = newpos[gi];
        else { int m = map[gi]; map[gi] = (m >= 0) ? newpos[m] : -1; }
        return;
    }
    int g = blk & 7, i = blk >> 3;
    int r = t >> 4, c = t & 15;          // 16 rows x 16 float4 cols
    int nn = g * k + i * 16 + r;
    int old = perm[nn];
    float2 m = mean[old];
    float2 xn = x2[old];
    float4 wl01 = ((const float4*)Wl1)[c * 2];      // (Wl[4c].x,.y, Wl[4c+1].x,.y)
    float4 wl23 = ((const float4*)Wl1)[c * 2 + 1];
    float4 wr01 = ((const float4*)Wr1)[c * 2];
    float4 wr23 = ((const float4*)Wr1)[c * 2 + 1];
    float4 bl   = ((const float4*)bl1)[c];
    float4 v;
    v.x = fmaxf(wl01.x * m.x + wl01.y * m.y + bl.x + wr01.x * xn.x + wr01.y * xn.y, 0.f);
    v.y = fmaxf(wl01.z * m.x + wl01.w * m.y + bl.y + wr01.z * xn.x + wr01.w * xn.y, 0.f);
    v.z = fmaxf(wl23.x * m.x + wl23.y * m.y + bl.z + wr23.x * xn.x + wr23.y * xn.y, 0.f);
    v.w = fmaxf(wl23.z * m.x + wl23.w * m.y + bl.w + wr23.z * xn.x + wr23.w * xn.y, 0.f);
    float sc = score[old];
    v.x *= sc; v.y *= sc; v.z *= sc; v.w *= sc;
    ((float4*)(hout + (size_t)nn * 64))[c] = v;
    sred[0][r][c * 4 + 0] = v.x; sred[0][r][c * 4 + 1] = v.y;
    sred[0][r][c * 4 + 2] = v.z; sred[0][r][c * 4 + 3] = v.w;
    sred[1][r][c * 4 + 0] = v.x; sred[1][r][c * 4 + 1] = v.y;
    sred[1][r][c * 4 + 2] = v.z; sred[1][r][c * 4 + 3] = v.w;
    __syncthreads();
    if (t < 64) {
        float mx = sred[0][0][t], sm = sred[1][0][t];
        for (int rr = 1; rr < 16; rr++) {
            mx = fmaxf(mx, sred[0][rr][t]);
            sm += sred[1][rr][t];
        }
        partial[(size_t)blk * 128 + t] = mx;
        partial[(size_t)blk * 128 + 64 + t] = sm;
    }
}

// ---------------------------------------------------------------------------
// SAGE round 2, transform-first, float4-vectorized gather.
// ---------------------------------------------------------------------------
__global__ void k_sage_gather2(const float* __restrict__ gl, const int* __restrict__ off,
                               const int* __restrict__ deg, const int* __restrict__ csrc,
                               const int* __restrict__ map,
                               const int* __restrict__ orig, const float* __restrict__ wp,
                               const float* __restrict__ invn,
                               float* __restrict__ own_in,
                               float* __restrict__ out, float* __restrict__ score, int ng) {
    int blk = blockIdx.x;
    int g = blk & 7, i = blk >> 3;
    int wv = threadIdx.x >> 6, l = threadIdx.x & 63;
    int n = g * ng + i * 4 + wv;
    int o = orig[n];
    int beg = off[o], end = beg + deg[o];
    int fg = l & 15, es = l >> 4;
    float4 own = make_float4(0.f, 0.f, 0.f, 0.f);
    if (es == 0) own = ((const float4*)(own_in + (size_t)n * 64))[fg];
    float4 acc = make_float4(0.f, 0.f, 0.f, 0.f);
    int cnt = 0;
    for (int base = beg; base < end; base += 64) {
        int d = end - base; if (d > 64) d = 64;
        int cs = (l < d) ? map[csrc[base + l]] : -1;
        cnt += __popcll(__ballot(cs >= 0));
        for (int e = 0; e < d; e += 4) {
            int c = __shfl(cs, e + es);
            if (c >= 0) {
                float4 v = ((const float4*)(gl + (size_t)c * 64))[fg];
                acc.x += v.x; acc.y += v.y; acc.z += v.z; acc.w += v.w;
            }
        }
    }
    acc.x += __shfl_xor(acc.x, 16); acc.y += __shfl_xor(acc.y, 16);
    acc.z += __shfl_xor(acc.z, 16); acc.w += __shfl_xor(acc.w, 16);
    acc.x += __shfl_xor(acc.x, 32); acc.y += __shfl_xor(acc.y, 32);
    acc.z += __shfl_xor(acc.z, 32); acc.w += __shfl_xor(acc.w, 32);
    float c = fmaxf((float)cnt, 1.0f);
    float4 v;
    v.x = fmaxf(acc.x / c + own.x, 0.f);
    v.y = fmaxf(acc.y / c + own.y, 0.f);
    v.z = fmaxf(acc.z / c + own.z, 0.f);
    v.w = fmaxf(acc.w / c + own.w, 0.f);
    float dsc = 0.f;
    if (es == 0) {
        ((float4*)(out + (size_t)n * 64))[fg] = v;
        float4 w4 = ((const float4*)wp)[fg];
        dsc = v.x * w4.x + v.y * w4.y + v.z * w4.z + v.w * w4.w;
    }
    for (int o2 = 32; o2; o2 >>= 1) dsc += __shfl_xor(dsc, o2);
    if (l == 0) score[n] = dsc * invn[0];
}

// GCN gather, float4-vectorized.
__global__ void k_gcn_gather(const float* __restrict__ xw, const int* __restrict__ off,
                             const int* __restrict__ deg, const int* __restrict__ csrc,
                             const int* __restrict__ map,
                             const int* __restrict__ orig, const float* __restrict__ dis,
                             const float* __restrict__ bb, const float* __restrict__ wp,
                             const float* __restrict__ invn,
                             float* __restrict__ out, float* __restrict__ score, int ng) {
    int blk = blockIdx.x;
    int g = blk & 7, i = blk >> 3;
    int wv = threadIdx.x >> 6, l = threadIdx.x & 63;
    int n = g * ng + i * 4 + wv;
    int o = orig[n];
    int beg = off[o], end = beg + deg[o];
    int fg = l & 15, es = l >> 4;
    float dn = dis[n];
    float4 own = make_float4(0.f, 0.f, 0.f, 0.f);
    if (es == 0) own = ((const float4*)(xw + (size_t)n * 64))[fg];
    float4 acc = make_float4(0.f, 0.f, 0.f, 0.f);
    for (int base = beg; base < end; base += 64) {
        int d = end - base; if (d > 64) d = 64;
        int cs = -1; float dsv = 0.f;
        if (l < d) {
            int cc = map[csrc[base + l]];
            if (cc >= 0) { cs = cc; dsv = dis[cc]; }
        }
        for (int e = 0; e < d; e += 4) {
            int c = __shfl(cs, e + es);
            float dv = __shfl(dsv, e + es);
            if (c >= 0) {
                float4 v = ((const float4*)(xw + (size_t)c * 64))[fg];
                acc.x += v.x * dv; acc.y += v.y * dv;
                acc.z += v.z * dv; acc.w += v.w * dv;
            }
        }
    }
    acc.x += __shfl_xor(acc.x, 16); acc.y += __shfl_xor(acc.y, 16);
    acc.z += __shfl_xor(acc.z, 16); acc.w += __shfl_xor(acc.w, 16);
    acc.x += __shfl_xor(acc.x, 32); acc.y += __shfl_xor(acc.y, 32);
    acc.z += __shfl_xor(acc.z, 32); acc.w += __shfl_xor(acc.w, 32);
    float dsc = 0.f;
    if (es == 0) {
        float4 b4 = ((const float4*)bb)[fg];
        float dd = dn * dn;
        float4 v;
        v.x = fmaxf(acc.x * dn + own.x * dd + b4.x, 0.f);
        v.y = fmaxf(acc.y * dn + own.y * dd + b4.y, 0.f);
        v.z = fmaxf(acc.z * dn + own.z * dd + b4.z, 0.f);
        v.w = fmaxf(acc.w * dn + own.w * dd + b4.w, 0.f);
        ((float4*)(out + (size_t)n * 64))[fg] = v;
        float4 w4 = ((const float4*)wp)[fg];
        dsc = v.x * w4.x + v.y * w4.y + v.z * w4.z + v.w * w4.w;
    }
    for (int o2 = 32; o2; o2 >>= 1) dsc += __shfl_xor(dsc, o2);
    if (l == 0) score[n] = dsc * invn[0];
}

// ---------------------------------------------------------------------------
// Parallel partial reduction: 960 part-blocks per graph split into 16 slices
// of 60. 128 blocks (8 graphs x 16 slices) x 256 threads. Round-specific
// mean scaling applied here (sum lanes j>=64). Output red2[(slice*8+g)*128+j].
// ---------------------------------------------------------------------------
__global__ void k_zred(const float* __restrict__ part, float* __restrict__ red2) {
    __shared__ float sred[2][128];
    int b2 = blockIdx.x;
    int g = b2 & 7, slice = b2 >> 3;
    int t = threadIdx.x;
    int j = t & 127, h = t >> 7;          // 2 half-slices of 30
    int pb0 = slice * 60 + h * 30;
    float accm = -3.0e38f, accs = 0.f;
    for (int pb = pb0; pb < pb0 + 30; pb++) {
        const float* p; int i; float scale;
        if (pb < 512)      { p = part + P1; i = pb;       scale = 1.0f / 8192.0f; }
        else if (pb < 768) { p = part + P2; i = pb - 512; scale = 1.0f / 4096.0f; }
        else if (pb < 896) { p = part + P3; i = pb - 768; scale = 1.0f / 2048.0f; }
        else               { p = part + P4; i = pb - 896; scale = 1.0f / 1024.0f; }
        float v = p[(size_t)(i * 8 + g) * 128 + j];
        accm = fmaxf(accm, v);
        accs += v * scale;
    }
    sred[h][j] = (j < 64) ? accm : accs;
    __syncthreads();
    if (t < 128) {
        float out = (j < 64) ? fmaxf(sred[0][j], sred[1][j]) : (sred[0][j] + sred[1][j]);
        red2[(size_t)b2 * 128 + j] = out;
    }
}

// ---------------------------------------------------------------------------
// Fused z assembly (from red2, 16 entries/graph) + MLP + softmax.
// 8 blocks x 1024 threads.
// ---------------------------------------------------------------------------
__global__ void k_mlpz(const float* __restrict__ red2,
                       const float* __restrict__ WaT, const float* __restrict__ ba,
                       const float* __restrict__ WbT, const float* __restrict__ bb,
                       const float* __restrict__ WcT, const float* __restrict__ bc,
                       float* __restrict__ out) {
    __shared__ float red[8][128];
    __shared__ float sz[128];
    __shared__ float sa[128];
    __shared__ float sb2[64];
    __shared__ float sc[256];
    __shared__ float tmp[256];
    __shared__ float wred[4];
    int b = blockIdx.x, t = threadIdx.x;
    int j = t & 127, s = t >> 7;           // s in 0..7; 2 slices each
    {
        float v0 = red2[(size_t)((s * 2 + 0) * 8 + b) * 128 + j];
        float v1 = red2[(size_t)((s * 2 + 1) * 8 + b) * 128 + j];
        red[s][j] = (j < 64) ? fmaxf(v0, v1) : (v0 + v1);
    }
    __syncthreads();
    if (t < 128) {
        float zv;
        if (j < 64) {
            float m1 = fmaxf(fmaxf(red[0][j], red[1][j]), fmaxf(red[2][j], red[3][j]));
            float m2 = fmaxf(fmaxf(red[4][j], red[5][j]), fmaxf(red[6][j], red[7][j]));
            zv = fmaxf(m1, m2);
        } else {
            zv = ((red[0][j] + red[1][j]) + (red[2][j] + red[3][j]))
               + ((red[4][j] + red[5][j]) + (red[6][j] + red[7][j]));
        }
        sz[t] = zv;
    }
    __syncthreads();
    if (t < 256) {
        int o = t & 127, half = t >> 7;
        float v = 0.f;
        int q0 = half * 64;
        for (int q = q0; q < q0 + 64; q++) v += sz[q] * WaT[q * 128 + o];
        tmp[t] = v;
    }
    __syncthreads();
    if (t < 128) sa[t] = fmaxf(tmp[t] + tmp[t + 128] + ba[t], 0.f);
    __syncthreads();
    if (t < 256) {
        int o = t & 63, qr = t >> 6;
        float v = 0.f;
        int q0 = qr * 32;
        for (int q = q0; q < q0 + 32; q++) v += sa[q] * WbT[q * 64 + o];
        tmp[t] = v;
    }
    __syncthreads();
    if (t < 64) sb2[t] = fmaxf(tmp[t] + tmp[t + 64] + tmp[t + 128] + tmp[t + 192] + bb[t], 0.f);
    __syncthreads();
    if (t < 256) {
        float v = bc[t];
        for (int q = 0; q < 64; q++) v += sb2[q] * WcT[q * 256 + t];
        sc[t] = v;
    }
    __syncthreads();
    if (t < 256) {
        float m = sc[t];
        for (int o2 = 32; o2; o2 >>= 1) m = fmaxf(m, __shfl_xor(m, o2));
        if ((t & 63) == 0) wred[t >> 6] = m;
    }
    __syncthreads();
    float m = fmaxf(fmaxf(wred[0], wred[1]), fmaxf(wred[2], wred[3]));
    __syncthreads();
    if (t < 256) {
        float e = expf(sc[t] - m);
        tmp[t] = e;
        float ss = e;
        for (int o2 = 32; o2; o2 >>= 1) ss += __shfl_xor(ss, o2);
        if ((t & 63) == 0) wred[t >> 6] = ss;
    }
    __syncthreads();
    if (t < 256) {
        float ss = wred[0] + wred[1] + wred[2] + wred[3];
        out[b * 256 + t] = tmp[t] / ss;
    }
}

// ---------------------------------------------------------------------------
extern "C" void kernel_launch(void* const* d_in, const int* in_sizes, int n_in,
                              void* d_out, int out_size, void* d_ws, size_t ws_size,
                              hipStream_t stream) {
    const float* x   = (const float*)d_in[0];
    const int*   ei  = (const int*)d_in[1];
    const int* src = ei;
    const int* dst = ei + Eq;
    const float* Wl1 = (const float*)d_in[2];
    const float* bl1 = (const float*)d_in[3];
    const float* Wr1 = (const float*)d_in[4];
    const float* Wl2 = (const float*)d_in[5];
    const float* bl2 = (const float*)d_in[6];
    const float* Wr2 = (const float*)d_in[7];
    const float* W4  = (const float*)d_in[8];
    const float* b4  = (const float*)d_in[9];
    const float* W5  = (const float*)d_in[10];
    const float* b5  = (const float*)d_in[11];
    const float* wp1 = (const float*)d_in[12];
    const float* wp2 = (const float*)d_in[13];
    const float* wp4 = (const float*)d_in[14];
    const float* wp5 = (const float*)d_in[15];
    const float* Wa  = (const float*)d_in[16];
    const float* ba  = (const float*)d_in[17];
    const float* Wb  = (const float*)d_in[18];
    const float* bbv = (const float*)d_in[19];
    const float* Wc  = (const float*)d_in[20];
    const float* bc  = (const float*)d_in[21];
    float* out = (float*)d_out;

    const int N1 = Nq / 2, N2 = Nq / 4, N3 = Nq / 8, N4 = Nq / 16;

    // workspace layout
    char* w = (char*)d_ws;
    float* hA    = (float*)w; w += (size_t)Nq * 64 * 4;        // 33.5 MB
    float* hB    = (float*)w; w += (size_t)N1 * 64 * 4;        // 16.8 MB (pooled rows)
    float* hC    = (float*)w; w += (size_t)N1 * 64 * 4;        // 16.8 MB (gl / xw)
    int*   csrc  = (int*)w;   w += (size_t)512 * BCAP * 4;     // 16.8 MB (bucketed)
    int*   coff  = (int*)w;   w += (size_t)(Nq + 1) * 4;
    int*   degA  = (int*)w;   w += (size_t)Nq * 4;             // per-node degree
    int*   bcur  = (int*)w;   w += (size_t)Nq * 4;             // 512 used; winv in tail
    int*   cnt   = (int*)w;   w += (size_t)Nq * 4;             // aliased by mean (lo)
    float* dis   = (float*)w; w += (size_t)Nq * 4;             // aliased by mean (hi)
    float* score = (float*)w; w += (size_t)Nq * 4;
    int*   newpos= (int*)w;   w += (size_t)Nq * 4;
    int*   map   = (int*)w;   w += (size_t)Nq * 4;
    int*   perm  = (int*)w;   w += (size_t)Nq * 4;
    int*   origA = (int*)w;   w += (size_t)Nq * 4;
    int*   origB = (int*)w;   w += (size_t)Nq * 4;
    float* part  = (float*)w; w += (size_t)PTOT * 4;           // 3.93 MB partials
    float* red2  = (float*)w; w += (size_t)128 * 128 * 4;      // 64 KB slice partials
    float* wT    = (float*)w; w += 4 * 4096 * 4;               // 64 KB
    float* wMT   = (float*)w; w += (16384 + 8192 + 16384) * 4; // 160 KB
    float* WlT2 = wT, *WrT2 = wT + 4096, *W4T = wT + 8192, *W5T = wT + 12288;
    float* WaT = wMT, *WbT = wMT + 16384, *WcT = wMT + 16384 + 8192;
    unsigned* pairs = (unsigned*)hA;      // CSR staging aliases hA (free then)
    float2* mean = (float2*)cnt;          // Nq float2 spans cnt+dis (dis used later)
    float* winv = (float*)(bcur + 1024);  // 4 floats in free tail of bcur slot

    // ---- One-time: prep (transposes + wnorm + bcur zero) + CSR build
    // (k_csr_b also emits the round-1 mean AND round-1 score)
    k_prep<<<8, 256, 0, stream>>>(Wl2, Wr2, W4, W5, Wa, Wb, Wc,
                                  wp1, wp2, wp4, wp5, wT, wMT, winv, bcur);
    k_csr_a<<<256, 1024, 0, stream>>>(src, dst, bcur, pairs);
    k_csr_b<<<512, 256, 0, stream>>>(bcur, pairs, (const float2*)x, coff, degA, csrc, mean,
                                     Wl1, bl1, Wr1, wp1, winv, score);

    // ---- Round 1: topk, compact-recompute(+partials+map) -> hB
    k_topk<16><<<8, 1024, 0, stream>>>(score, newpos, perm, nullptr, origA, 1);
    k_compact4r<<<4096 + 512, 256, 0, stream>>>(mean, (const float2*)x, Wl1, bl1, Wr1,
                                                score, perm, hB, N1 / 8, part + P1,
                                                newpos, map, 1, 4096);

    // ---- Round 2: fused [hB@Wl->hC | hB@Wr+bl->hA] then gather
    k_linf<<<512 + 512, 256, 0, stream>>>(hB,
                                          WlT2, hC, 512,
                                          WrT2, bl2, hA, 512,
                                          N1,
                                          nullptr, nullptr, nullptr, nullptr, nullptr,
                                          nullptr, 0);
    k_sage_gather2<<<N1 / 4, 256, 0, stream>>>(hC, coff, degA, csrc, map, origA,
                                               wp2, winv + 1, hA, hA, score, N1 / 8);
    k_topk<8><<<8, 1024, 0, stream>>>(score, newpos, perm, origA, origB, 2);
    k_compact4<<<2048 + 512, 256, 0, stream>>>(hA, score, perm, hB, N2 / 8, part + P2,
                                               newpos, map, 2, 2048);

    // ---- Round 3: fused [hB@W4->hC | dis] then gather
    k_linf<<<512 + 8192, 256, 0, stream>>>(hB,
                                           W4T, hC, 512,
                                           nullptr, nullptr, nullptr, 0,
                                           N2,
                                           coff, degA, csrc, map, origB,
                                           dis, N2 / 8);
    k_gcn_gather<<<N2 / 4, 256, 0, stream>>>(hC, coff, degA, csrc, map, origB, dis,
                                             b4, wp4, winv + 2, hA, score, N2 / 8);
    k_topk<4><<<8, 1024, 0, stream>>>(score, newpos, perm, origB, origA, 2);
    k_compact4<<<1024 + 512, 256, 0, stream>>>(hA, score, perm, hB, N3 / 8, part + P3,
                                               newpos, map, 2, 1024);

    // ---- Round 4: fused [hB@W5->hC | dis] then gather
    k_linf<<<256 + 4096, 256, 0, stream>>>(hB,
                                           W5T, hC, 256,
                                           nullptr, nullptr, nullptr, 0,
                                           N3,
                                           coff, degA, csrc, map, origA,
                                           dis, N3 / 8);
    k_gcn_gather<<<N3 / 4, 256, 0, stream>>>(hC, coff, degA, csrc, map, origA, dis,
                                             b5, wp5, winv + 3, hA, score, N3 / 8);
    k_topk<2><<<8, 1024, 0, stream>>>(score, newpos, perm, nullptr, nullptr, 0);
    k_compact4<<<512, 256, 0, stream>>>(hA, score, perm, hB, N4 / 8, part + P4,
                                        newpos, map, 0, 512);

    // ---- parallel z reduction, then MLP + softmax
    k_zred<<<128, 256, 0, stream>>>(part, red2);
    k_mlpz<<<8, 1024, 0, stream>>>(red2, WaT, ba, WbT, bbv, WcT, bc, out);
}